// Round 7
// baseline (2060.548 us; speedup 1.0000x reference)
//
#include <hip/hip_runtime.h>
#include <stdint.h>

// Conductance-LIF network, persistent event-driven kernel. Round 7.
//
// Rounds 3-6 post-mortem: per-wave gather is ~10 loads/step — the ~2.5 us step
// was pure sync convoy: fabric visibility + serial poll + BLOCK BARRIER +
// LDS reduce around every step. This round dissolves the block:
//
//   * grid = 768 single-wave blocks (64 thr). Wave = one (batch, 64-col
//     stripe). Lane = neuron: the three conductance sums are per-lane scalars
//     -> NO cross-wave reduction, NO LDS, NO __syncthreads in the time loop.
//   * One 48-lane atomic load polls ALL 48 spike words of the batch in a
//     single instruction; detection is one compare + ballot. The first poll
//     is issued BEFORE the FF gather so its latency overlaps real work.
//   * FF masks: 12 per-lane I loads (prefetched one step ahead) + 12 ballots
//     -> wave-uniform 64-bit masks in SGPRs; FF rows gathered directly.
//   * Row loop is SALU+VMEM dominated: spike bits live in SGPRs (readlane),
//     per row ~4 scalar ops + one 256 B coalesced load (64 lanes x 4 B).
//   * Publish = 2 words/stripe (lanes 0 and 32), BEFORE output stores.
//
// Mapping: blockIdx = x + 8*(3*b + sub), x=0..7 -> XCD under %8 round-robin;
// stripe s = 3*x + sub covers cols [64s, 64s+64) so each XCD's working set is
// a fixed 192-col slice of W+WF (1.77 MB, L2-resident). Placement is a perf
// heuristic only — correctness never depends on it.
//
// Sync (unchanged, fence-free): flag+data in ONE 64-bit word, hi32 = step tag
// (t+1), lo32 = 32 spike bits; relaxed agent-scope atomics only (no acquire /
// release -> no buffer_inv -> L2 stays warm). Tags 1..256 never collide with
// the 0xAAAAAAAA ws poison. All 768 blocks are trivially co-resident (1 wave,
// 0 LDS each; 3 blocks/CU) and each wave publishes step t before waiting on
// step-t words -> induction over t, no deadlock.

__global__ __launch_bounds__(64) void snn_lif_kernel(
    const float* __restrict__ I,     // [32][256][768] input spikes (0/1)
    const float* __restrict__ W,     // [1536][1536] recurrent weights (row = pre)
    const float* __restrict__ WF,    // [768][1536]  FF weights (row = input)
    const float* __restrict__ sf,    // [2][2] scaling (pre ct, post ct)
    const float* __restrict__ sfF,   // [1][2] FF scaling (post ct)
    const int*   __restrict__ ct,    // [1536] cell type 0/1
    float* __restrict__ out,         // spk [32][256][1536] then volt [...]
    uint64_t* __restrict__ recpub)   // [32][256][48]: (tag<<32)|spike-bits
{
    const int wl  = threadIdx.x;          // lane 0..63
    const int x   = blockIdx.x & 7;       // XCD slot under %8 RR
    const int k   = blockIdx.x >> 3;      // 0..95
    const int b   = k / 3;                // batch 0..31
    const int sub = k - 3 * b;            // 0..2
    const int s   = 3 * x + sub;          // stripe 0..23 (cols [64s,64s+64))
    const int m   = s * 64 + wl;          // owned neuron / column
    const int btbase = b * 256;

    // per-lane ct bit-word: lane l (<48) holds the 32 cell-type bits of
    // spike-word l (neurons 32l..32l+31). One-time, L2-amortized.
    uint32_t cmv = 0;
    if (wl < 48) {
        #pragma unroll
        for (int i = 0; i < 32; ++i)
            cmv |= (uint32_t)(ct[wl * 32 + i] != 0) << i;
    }

    // ---- owner-neuron constants (per lane) ----
    const int   myct = ct[m];
    const float s0m  = sf[myct];
    const float s1m  = sf[2 + myct];
    const float sFm  = sfF[myct];
    const float lc   = (myct == 0) ? (1.0f / 200.0f) : (1.0f / 100.0f);
    const float refsteps = (myct == 0) ? 2.0f : 1.0f;
    const float ar0 = expf(-1.0f / 0.5f),  ad0 = expf(-1.0f / 2.0f);
    const float ar1 = expf(-1.0f / 2.0f),  ad1 = expf(-1.0f / 100.0f);
    const float ar2 = expf(-1.0f / 0.5f),  ad2 = expf(-1.0f / 5.0f);
    const float arF = expf(-1.0f / 0.5f),  adF = expf(-1.0f / 2.0f);

    float U = -65.0f, refc = 0.0f;
    float x0 = 0, g0 = 0, x1 = 0, g1 = 0, x2 = 0, g2 = 0, xF = 0, gF = 0;

    // initial I prefetch (step 0): lane wl covers inputs c*64+wl, c=0..11
    float ivv[12];
    {
        const float* Ib = I + (uint32_t)btbase * 768u;
        #pragma unroll
        for (int c = 0; c < 12; ++c)
            ivv[c] = __builtin_nontemporal_load(&Ib[c * 64 + wl]);
    }

    const uint64_t need = 0x0000FFFFFFFFFFFFull;   // 48 words

    for (int t = 0; t < 256; ++t) {
        // ---- FF masks for this step (wave-uniform SGPR masks) ----
        uint64_t fm[12];
        #pragma unroll
        for (int c = 0; c < 12; ++c) fm[c] = __ballot(ivv[c] > 0.5f);

        // issue first poll of this step NOW (latency overlaps FF gather)
        const uint64_t* pp = recpub + (uint32_t)(btbase + t - 1) * 48u;
        uint64_t pv = 0;
        if (t > 0 && wl < 48)
            pv = __hip_atomic_load(pp + wl, __ATOMIC_RELAXED,
                                   __HIP_MEMORY_SCOPE_AGENT);

        // prefetch next-step inputs (in flight behind gather/poll)
        if (t < 255) {
            const float* Ib = I + (uint32_t)(btbase + t + 1) * 768u;
            #pragma unroll
            for (int c = 0; c < 12; ++c)
                ivv[c] = __builtin_nontemporal_load(&Ib[c * 64 + wl]);
        }

        float z0 = 0.f, z1 = 0.f, zF = 0.f;

        // ---- FF gather: rows over this stripe's 64 cols (256 B/row) ----
        #pragma unroll
        for (int c = 0; c < 12; ++c) {
            uint64_t mm = fm[c];
            while (mm) {
                const int bit = __builtin_ctzll(mm);
                mm &= mm - 1;
                zF += WF[(uint32_t)(c * 64 + bit) * 1536u + (uint32_t)m];
            }
        }

        // ---- poll all 48 words (one 48-lane load); gather on arrival ----
        if (t > 0) {
            uint64_t done = 0;
            for (;;) {
                const uint64_t arr = __ballot((uint32_t)(pv >> 32) == (uint32_t)t);
                uint64_t neww = arr & ~done;
                done |= neww;
                const uint32_t pvlo = (uint32_t)pv;
                while (neww) {
                    const int w = __builtin_ctzll(neww);
                    neww &= neww - 1;
                    uint32_t bits = __builtin_amdgcn_readlane(pvlo, w);
                    const uint32_t cm = __builtin_amdgcn_readlane(cmv, w);
                    const uint32_t rowbase = (uint32_t)w * 32u;
                    while (bits) {
                        const int bit = __builtin_ctz(bits);
                        bits &= bits - 1;
                        const float wv_ = W[(rowbase + (uint32_t)bit) * 1536u + (uint32_t)m];
                        if ((cm >> bit) & 1u) z1 += wv_;   // wave-uniform branch
                        else                  z0 += wv_;
                    }
                }
                if (done == need) break;
                pv = 0;
                if (wl < 48)
                    pv = __hip_atomic_load(pp + wl, __ATOMIC_RELAXED,
                                           __HIP_MEMORY_SCOPE_AGENT);
            }
        }

        // ---- LIF update (per lane = per neuron) ----
        z0 *= s0m; z1 *= s1m; zF *= sFm;
        x0 = ar0 * x0 + z0;  g0 = ad0 * g0 + x0;   // syn0 (pre ct0)
        x1 = ar1 * x1 + z0;  g1 = ad1 * g1 + x1;   // syn1 (pre ct0, same z0)
        x2 = ar2 * x2 + z1;  g2 = ad2 * g2 + x2;   // syn2 (pre ct1)
        xF = arF * xF + zF;  gF = adF * gF + xF;   // feed-forward
        const float gtot = g0 + 0.5f * g1 + g2 + gF;   // gbar=[1,.5,1], FF 1
        const float gE   = -70.0f * g2;                // gbar*Erev=[0,0,-70], FF 0
        const float Isyn = gE - gtot * U;
        float Un = U + lc * (10.0f * (-65.0f - U) + Isyn);
        if (refc > 0.0f) Un = -65.0f;
        refc = fmaxf(refc - 1.0f, 0.0f);
        const bool sp = (Un - (-50.0f)) >= 0.0f;

        // ---- publish FIRST (lanes 0/32: tag+bits in one 64-bit word) ----
        const uint64_t bal = __ballot(sp);
        if (wl == 0 || wl == 32) {
            const uint32_t bits = (wl == 0) ? (uint32_t)bal : (uint32_t)(bal >> 32);
            const uint32_t widx = (uint32_t)(btbase + t) * 48u
                                + (uint32_t)(s * 2) + (wl == 32 ? 1u : 0u);
            const uint64_t v = ((uint64_t)(uint32_t)(t + 1) << 32) | bits;
            __hip_atomic_store(&recpub[widx], v, __ATOMIC_RELAXED,
                               __HIP_MEMORY_SCOPE_AGENT);
        }

        const float Uo = sp ? -65.0f : Un;
        refc = sp ? refsteps : refc;
        U = Uo;
        const uint32_t oidx = (uint32_t)(btbase + t) * 1536u + (uint32_t)m;
        __builtin_nontemporal_store(sp ? 1.0f : 0.0f, &out[oidx]);
        __builtin_nontemporal_store(Uo, &out[12582912u + oidx]);
    }
}

extern "C" void kernel_launch(void* const* d_in, const int* in_sizes, int n_in,
                              void* d_out, int out_size, void* d_ws, size_t ws_size,
                              hipStream_t stream) {
    const float* I   = (const float*)d_in[0];   // input_spikes (32,256,768)
    const float* W   = (const float*)d_in[1];   // weights (1536,1536)
    const float* WF  = (const float*)d_in[2];   // weights_FF (768,1536)
    const float* sf  = (const float*)d_in[3];   // scaling_factors (2,2)
    const float* sfF = (const float*)d_in[4];   // scaling_factors_FF (1,2)
    const int*   ct  = (const int*)d_in[5];     // cell_type_indices (1536)
    // d_in[6] cell_type_indices_FF: all zeros, folded into sfF indexing.

    uint64_t* recpub = (uint64_t*)d_ws;   // 32*256*48*8 = 3,145,728 B

    snn_lif_kernel<<<dim3(768), dim3(64), 0, stream>>>(
        I, W, WF, sf, sfF, ct, (float*)d_out, recpub);
}